// Round 1
// baseline (43232.211 us; speedup 1.0000x reference)
//
#include <hip/hip_runtime.h>
#include <math.h>

#define SEQ 128
#define B 64
#define NN 128
#define IN_DIM 64
#define HID 128
#define BNH (B*NN*HID)   // 1,048,576

// ---------------- A2 = [S ; 2*S^2 - I]  (256 x 128) ----------------
__global__ void compute_A2_kernel(const float* __restrict__ S, float* __restrict__ A2) {
    int idx = blockIdx.x * 256 + threadIdx.x;     // 16384 threads total
    int m = idx >> 7, n = idx & 127;
    A2[idx] = S[idx];                             // rows 0..127 = S
    float acc = 0.f;
    #pragma unroll 4
    for (int k = 0; k < 128; ++k) acc += S[m*128 + k] * S[k*128 + n];
    A2[16384 + idx] = 2.f*acc - (m == n ? 1.f : 0.f);  // rows 128..255 = 2S^2 - I
}

// ------------- build cat = [x_in, (r*)h]; write catbuf + xs slot m=0 -------------
template<bool CAND>
__global__ void build_cat_kernel(const float* __restrict__ xin, int Fin,
                                 const float* __restrict__ h,
                                 const float* __restrict__ gates,
                                 float* __restrict__ catbuf,
                                 float* __restrict__ xs,
                                 int F, int KK) {
    int idx = blockIdx.x * 256 + threadIdx.x;   // over B*N*F
    int f  = idx % F;
    int bn = idx / F;
    float v;
    if (f < Fin) {
        v = xin[(size_t)bn * Fin + f];
    } else {
        int o = f - Fin;
        float hv = h[(size_t)bn * HID + o];
        if (CAND) hv *= gates[(size_t)bn * 256 + o];   // r (post-sigmoid)
        v = hv;
    }
    catbuf[(size_t)bn * F + f] = v;
    xs[(size_t)bn * KK + 3*f] = v;              // torch layout: k = f*M + m, m=0
}

// ------------- diffusion GEMM: out[m',f] = A2[m',:] @ cat[b,:,f] -------------
// m' in [0,128) -> xs slot m=1 (x1 = S@cat); m' in [128,256) -> slot m=2 (x2 = (2S^2-I)@cat)
__global__ __launch_bounds__(256)
void diffuse_gemm_kernel(const float* __restrict__ A2,
                         const float* __restrict__ catbuf,
                         float* __restrict__ xs, int F, int KK) {
    __shared__ float As[16][68];
    __shared__ float Bs[16][68];
    const int b  = blockIdx.z;
    const int m0 = blockIdx.y * 64;
    const int f0 = blockIdx.x * 64;
    const float* catB = catbuf + (size_t)b * NN * F;
    const int tid = threadIdx.x;
    const int tx = tid & 15, ty = tid >> 4;
    float acc[4][4] = {};
    for (int k0 = 0; k0 < 128; k0 += 16) {
        #pragma unroll
        for (int i = 0; i < 4; ++i) {
            int e = tid + i*256;
            int m = e >> 4, k = e & 15;
            As[k][m] = A2[(m0 + m)*128 + k0 + k];
        }
        #pragma unroll
        for (int i = 0; i < 4; ++i) {
            int e = tid + i*256;
            int k = e >> 6, n = e & 63;
            Bs[k][n] = catB[(size_t)(k0 + k)*F + f0 + n];
        }
        __syncthreads();
        #pragma unroll
        for (int k = 0; k < 16; ++k) {
            float4 a4 = *(const float4*)&As[k][ty*4];
            float4 b4 = *(const float4*)&Bs[k][tx*4];
            float av[4] = {a4.x, a4.y, a4.z, a4.w};
            float bv[4] = {b4.x, b4.y, b4.z, b4.w};
            #pragma unroll
            for (int i = 0; i < 4; ++i)
                #pragma unroll
                for (int j = 0; j < 4; ++j) acc[i][j] += av[i]*bv[j];
        }
        __syncthreads();
    }
    #pragma unroll
    for (int i = 0; i < 4; ++i) {
        int gm = m0 + ty*4 + i;
        int node = (gm < 128) ? gm : gm - 128;
        int slot = (gm < 128) ? 1 : 2;
        float* dst = xs + ((size_t)b*NN + node)*KK + slot;
        #pragma unroll
        for (int j = 0; j < 4; ++j) {
            int gf = f0 + tx*4 + j;
            dst[3*gf] = acc[i][j];
        }
    }
}

// ------------- projection GEMM: (8192 x KK) @ (KK x NO) + bias, fused act -------------
// MODE 0: gates = sigmoid(..)  (NO=256)
// MODE 1: c = tanh(..); h = u*h + (1-u)*c; optionally also write outputs  (NO=128)
template<int MODE>
__global__ __launch_bounds__(256)
void proj_gemm_kernel(const float* __restrict__ A, const float* __restrict__ W,
                      const float* __restrict__ bias, int KK,
                      float* __restrict__ gates, float* __restrict__ h,
                      float* __restrict__ out2) {
    __shared__ float As[16][68];
    __shared__ float Bs[16][68];
    const int NO = (MODE == 0) ? 256 : 128;
    const int n0 = blockIdx.x * 64;
    const int m0 = blockIdx.y * 64;
    const int tid = threadIdx.x;
    const int tx = tid & 15, ty = tid >> 4;
    float acc[4][4] = {};
    for (int k0 = 0; k0 < KK; k0 += 16) {
        #pragma unroll
        for (int i = 0; i < 4; ++i) {
            int e = tid + i*256;
            int m = e >> 4, k = e & 15;
            As[k][m] = A[(size_t)(m0 + m)*KK + k0 + k];
        }
        #pragma unroll
        for (int i = 0; i < 4; ++i) {
            int e = tid + i*256;
            int k = e >> 6, n = e & 63;
            Bs[k][n] = W[(size_t)(k0 + k)*NO + n0 + n];
        }
        __syncthreads();
        #pragma unroll
        for (int k = 0; k < 16; ++k) {
            float4 a4 = *(const float4*)&As[k][ty*4];
            float4 b4 = *(const float4*)&Bs[k][tx*4];
            float av[4] = {a4.x, a4.y, a4.z, a4.w};
            float bv[4] = {b4.x, b4.y, b4.z, b4.w};
            #pragma unroll
            for (int i = 0; i < 4; ++i)
                #pragma unroll
                for (int j = 0; j < 4; ++j) acc[i][j] += av[i]*bv[j];
        }
        __syncthreads();
    }
    #pragma unroll
    for (int i = 0; i < 4; ++i) {
        int row = m0 + ty*4 + i;
        #pragma unroll
        for (int j = 0; j < 4; ++j) {
            int col = n0 + tx*4 + j;
            float v = acc[i][j] + bias[col];
            if (MODE == 0) {
                gates[(size_t)row*256 + col] = 1.f/(1.f + expf(-v));
            } else {
                float c = tanhf(v);
                float u = gates[(size_t)row*256 + 128 + col];
                float ho = h[(size_t)row*HID + col];
                float hn = u*ho + (1.f - u)*c;
                h[(size_t)row*HID + col] = hn;
                if (out2) out2[(size_t)row*HID + col] = hn;
            }
        }
    }
}

extern "C" void kernel_launch(void* const* d_in, const int* in_sizes, int n_in,
                              void* d_out, int out_size, void* d_ws, size_t ws_size,
                              hipStream_t stream) {
    (void)in_sizes; (void)n_in; (void)out_size; (void)ws_size;
    const float* inputs = (const float*)d_in[0];
    const float* h_init = (const float*)d_in[1];
    const float* S      = (const float*)d_in[2];
    const float* Wg0 = (const float*)d_in[3];
    const float* bg0 = (const float*)d_in[4];
    const float* Wc0 = (const float*)d_in[5];
    const float* bc0 = (const float*)d_in[6];
    const float* Wg1 = (const float*)d_in[7];
    const float* bg1 = (const float*)d_in[8];
    const float* Wc1 = (const float*)d_in[9];
    const float* bc1 = (const float*)d_in[10];

    float* out = (float*)d_out;
    float* h0 = out;                    // output_hidden layer 0 slot doubles as running h0
    float* h1 = out + BNH;              // layer 1 slot
    float* outputs = out + 2*(size_t)BNH;

    float* ws = (float*)d_ws;
    float* A2     = ws;                 // 32768 floats
    float* xs     = ws + 32768;         // B*N*768 = 6,291,456 floats
    float* catbuf = xs + 6291456;       // B*N*256 = 2,097,152 floats
    float* gates  = catbuf + 2097152;   // B*N*256 = 2,097,152 floats

    hipMemcpyAsync(h0, h_init, (size_t)2*BNH*sizeof(float),
                   hipMemcpyDeviceToDevice, stream);
    compute_A2_kernel<<<64, 256, 0, stream>>>(S, A2);

    for (int t = 0; t < SEQ; ++t) {
        const float* x0 = inputs + (size_t)t * B * NN * IN_DIM;
        // ---- layer 0 (F=192, KK=576) ----
        build_cat_kernel<false><<<6144, 256, 0, stream>>>(x0, IN_DIM, h0, nullptr, catbuf, xs, 192, 576);
        diffuse_gemm_kernel<<<dim3(3,4,B), 256, 0, stream>>>(A2, catbuf, xs, 192, 576);
        proj_gemm_kernel<0><<<dim3(4,128), 256, 0, stream>>>(xs, Wg0, bg0, 576, gates, nullptr, nullptr);
        build_cat_kernel<true><<<6144, 256, 0, stream>>>(x0, IN_DIM, h0, gates, catbuf, xs, 192, 576);
        diffuse_gemm_kernel<<<dim3(3,4,B), 256, 0, stream>>>(A2, catbuf, xs, 192, 576);
        proj_gemm_kernel<1><<<dim3(2,128), 256, 0, stream>>>(xs, Wc0, bc0, 576, gates, h0, nullptr);
        // ---- layer 1 (F=256, KK=768); input = ys0[t] = current h0 ----
        build_cat_kernel<false><<<8192, 256, 0, stream>>>(h0, HID, h1, nullptr, catbuf, xs, 256, 768);
        diffuse_gemm_kernel<<<dim3(4,4,B), 256, 0, stream>>>(A2, catbuf, xs, 256, 768);
        proj_gemm_kernel<0><<<dim3(4,128), 256, 0, stream>>>(xs, Wg1, bg1, 768, gates, nullptr, nullptr);
        build_cat_kernel<true><<<8192, 256, 0, stream>>>(h0, HID, h1, gates, catbuf, xs, 256, 768);
        diffuse_gemm_kernel<<<dim3(4,4,B), 256, 0, stream>>>(A2, catbuf, xs, 256, 768);
        proj_gemm_kernel<1><<<dim3(2,128), 256, 0, stream>>>(xs, Wc1, bc1, 768, gates, h1, outputs + (size_t)t*BNH);
    }
}

// Round 2
// 18674.747 us; speedup vs baseline: 2.3150x; 2.3150x over previous
//
#include <hip/hip_runtime.h>
#include <math.h>

#define SEQ 128
#define B 64
#define NN 128
#define IN_DIM 64
#define HID 128
#define BNH (B*NN*HID)   // 1,048,576

typedef unsigned short u16;
typedef __bf16 bf16x8 __attribute__((ext_vector_type(8)));
typedef float f32x4 __attribute__((ext_vector_type(4)));

__device__ __forceinline__ u16 f2bf(float f) {
    union { float f; unsigned u; } x; x.f = f;
    unsigned r = x.u + 0x7fffu + ((x.u >> 16) & 1u);
    return (u16)(r >> 16);
}

__device__ __forceinline__ bf16x8 ld_frag(const u16* p) {   // p must be 16B aligned
    union { uint4 q; bf16x8 v; } u;
    u.q = *(const uint4*)p;
    return u.v;
}

// ---------------- one-time prep ----------------
__global__ void prep_A2_kernel(const float* __restrict__ S, u16* __restrict__ A2bf) {
    int idx = blockIdx.x * 256 + threadIdx.x;   // 16384
    int m = idx >> 7, n = idx & 127;
    A2bf[idx] = f2bf(S[idx]);                   // rows 0..127 = S
    float acc = 0.f;
    #pragma unroll 4
    for (int k = 0; k < 128; ++k) acc += S[m*128 + k] * S[k*128 + n];
    A2bf[16384 + idx] = f2bf(2.f*acc - (m == n ? 1.f : 0.f));  // rows 128..255 = 2S^2-I
}

// WT[no][knew] = bf16(W[f*3+m][no]),  knew = m*F+f
__global__ void prep_WT_kernel(const float* __restrict__ W, u16* __restrict__ WT,
                               int F, int NO) {
    int KK = 3 * F;
    int idx = blockIdx.x * 256 + threadIdx.x;
    if (idx >= NO * KK) return;
    int no = idx / KK, knew = idx - no * KK;
    int m = knew / F, f = knew - m * F;
    WT[idx] = f2bf(W[(size_t)(f*3 + m) * NO + no]);
}

// ---------------- diffusion: D[f][m'] = sum_n cat[n][f] * A2[m'][n] ----------------
// writes xs = [x1 | x2] bf16, row = b*128+node, cols 2F
template<int FIN, int F, bool CAND>
__global__ __launch_bounds__(256) void diffuse_mfma(
    const float* __restrict__ X, const float* __restrict__ H,
    const float* __restrict__ gates, const u16* __restrict__ A2bf,
    u16* __restrict__ xs)
{
    __shared__ u16 At[64][40];    // catT chunk [f][node]
    __shared__ u16 Bt[128][40];   // A2 tile   [m'][n]
    const int b   = blockIdx.z;
    const int f0  = blockIdx.y * 64;
    const int mp0 = blockIdx.x * 128;
    const int tid = threadIdx.x;
    const int lane = tid & 63, w = tid >> 6;
    const int wf = w & 1, wm = w >> 1;
    const int l15 = lane & 15, l16 = lane >> 4;

    f32x4 acc[2][4];
    #pragma unroll
    for (int i = 0; i < 2; ++i)
        #pragma unroll
        for (int j = 0; j < 4; ++j) acc[i][j] = (f32x4)(0.f);

    for (int kc = 0; kc < 4; ++kc) {
        const int n0 = kc * 32;
        {   // stage catT (transpose): node = tid&31, f-group = tid>>5
            int node = tid & 31, fg = tid >> 5;
            int fbase = f0 + fg * 8;
            int bn = b*128 + n0 + node;
            float v[8];
            if (fbase < FIN) {
                const float* p = X + (size_t)bn * FIN + fbase;
                #pragma unroll
                for (int i = 0; i < 8; ++i) v[i] = p[i];
            } else {
                const float* p = H + (size_t)bn * HID + (fbase - FIN);
                #pragma unroll
                for (int i = 0; i < 8; ++i) v[i] = p[i];
                if (CAND) {
                    const float* pr = gates + (size_t)bn * 256 + (fbase - FIN);
                    #pragma unroll
                    for (int i = 0; i < 8; ++i) v[i] *= pr[i];
                }
            }
            #pragma unroll
            for (int i = 0; i < 8; ++i) At[fg*8 + i][node] = f2bf(v[i]);
        }
        {   // stage A2 tile: row = tid>>1, half = (tid&1)*16
            int row = tid >> 1, half = (tid & 1) * 16;
            const u16* p = A2bf + (size_t)(mp0 + row) * 128 + n0 + half;
            *(uint4*)&Bt[row][half]     = *(const uint4*)p;
            *(uint4*)&Bt[row][half + 8] = *(const uint4*)(p + 8);
        }
        __syncthreads();
        bf16x8 a[2], bb[4];
        #pragma unroll
        for (int i = 0; i < 2; ++i) a[i] = ld_frag(&At[wf*32 + i*16 + l15][l16*8]);
        #pragma unroll
        for (int j = 0; j < 4; ++j) bb[j] = ld_frag(&Bt[wm*64 + j*16 + l15][l16*8]);
        #pragma unroll
        for (int i = 0; i < 2; ++i)
            #pragma unroll
            for (int j = 0; j < 4; ++j)
                acc[i][j] = __builtin_amdgcn_mfma_f32_16x16x32_bf16(a[i], bb[j], acc[i][j], 0, 0, 0);
        __syncthreads();
    }
    // store D[f][m'] -> xs[b*128 + (m'&127)][(m'>>7)*F + f]
    #pragma unroll
    for (int i = 0; i < 2; ++i) {
        int fb = f0 + wf*32 + i*16 + l16*4;
        #pragma unroll
        for (int j = 0; j < 4; ++j) {
            int mp = mp0 + wm*64 + j*16 + l15;
            int node = mp & 127, slot = mp >> 7;
            u16* dst = xs + ((size_t)(b*128 + node)) * (2*F) + slot*F + fb;
            uint2 pk;
            pk.x = (unsigned)f2bf(acc[i][j][0]) | ((unsigned)f2bf(acc[i][j][1]) << 16);
            pk.y = (unsigned)f2bf(acc[i][j][2]) | ((unsigned)f2bf(acc[i][j][3]) << 16);
            *(uint2*)dst = pk;
        }
    }
}

// ---------------- projection: (8192 x 3F) @ (3F x NO) + bias, fused GRU ----------------
// MODE 0: gates = sigmoid (NO=256);  MODE 1: cand/tanh + GRU update (NO=128)
template<int FIN, int F, int MODE>
__global__ __launch_bounds__(256) void proj_mfma(
    const float* __restrict__ X, const float* __restrict__ H,
    const u16* __restrict__ xs, const u16* __restrict__ WT,
    const float* __restrict__ bias,
    float* __restrict__ gates, float* __restrict__ hout, float* __restrict__ out2)
{
    const int KK = 3 * F;
    __shared__ u16 At[128][40];
    __shared__ u16 Bt[64][40];
    const int m0 = blockIdx.y * 128;
    const int n0 = blockIdx.x * 64;
    const int tid = threadIdx.x;
    const int lane = tid & 63, w = tid >> 6;
    const int l15 = lane & 15, l16 = lane >> 4;

    f32x4 acc[2][4];
    #pragma unroll
    for (int i = 0; i < 2; ++i)
        #pragma unroll
        for (int j = 0; j < 4; ++j) acc[i][j] = (f32x4)(0.f);

    for (int k0 = 0; k0 < KK; k0 += 32) {
        {   // stage A: row = tid>>1, half = (tid&1)*16
            int row = tid >> 1, half = (tid & 1) * 16;
            int bn = m0 + row;
            int k = k0 + half;
            if (k >= F) {  // x1/x2 from xs (bf16)
                const u16* p = xs + (size_t)bn * (2*F) + (k - F);
                *(uint4*)&At[row][half]     = *(const uint4*)p;
                *(uint4*)&At[row][half + 8] = *(const uint4*)(p + 8);
            } else {
                float v[16];
                if (k < FIN) {
                    const float* p = X + (size_t)bn * FIN + k;
                    #pragma unroll
                    for (int i = 0; i < 16; ++i) v[i] = p[i];
                } else {
                    const float* p = H + (size_t)bn * HID + (k - FIN);
                    #pragma unroll
                    for (int i = 0; i < 16; ++i) v[i] = p[i];
                    if (MODE == 1) {
                        const float* pr = gates + (size_t)bn * 256 + (k - FIN);
                        #pragma unroll
                        for (int i = 0; i < 16; ++i) v[i] *= pr[i];
                    }
                }
                unsigned t[8];
                #pragma unroll
                for (int i = 0; i < 8; ++i)
                    t[i] = (unsigned)f2bf(v[2*i]) | ((unsigned)f2bf(v[2*i+1]) << 16);
                *(uint4*)&At[row][half]     = make_uint4(t[0], t[1], t[2], t[3]);
                *(uint4*)&At[row][half + 8] = make_uint4(t[4], t[5], t[6], t[7]);
            }
        }
        {   // stage B from WT: row = tid&63, quarter = tid>>6
            int r2 = tid & 63, q = tid >> 6;
            const u16* pw = WT + (size_t)(n0 + r2) * KK + k0 + q*8;
            *(uint4*)&Bt[r2][q*8] = *(const uint4*)pw;
        }
        __syncthreads();
        bf16x8 a[2], bb[4];
        #pragma unroll
        for (int i = 0; i < 2; ++i) a[i] = ld_frag(&At[w*32 + i*16 + l15][l16*8]);
        #pragma unroll
        for (int j = 0; j < 4; ++j) bb[j] = ld_frag(&Bt[j*16 + l15][l16*8]);
        #pragma unroll
        for (int i = 0; i < 2; ++i)
            #pragma unroll
            for (int j = 0; j < 4; ++j)
                acc[i][j] = __builtin_amdgcn_mfma_f32_16x16x32_bf16(a[i], bb[j], acc[i][j], 0, 0, 0);
        __syncthreads();
    }
    // epilogue
    #pragma unroll
    for (int i = 0; i < 2; ++i) {
        int rb = m0 + w*32 + i*16 + l16*4;
        #pragma unroll
        for (int j = 0; j < 4; ++j) {
            int col = n0 + j*16 + l15;
            float bcol = bias[col];
            #pragma unroll
            for (int r = 0; r < 4; ++r) {
                int row = rb + r;
                float v = acc[i][j][r] + bcol;
                if (MODE == 0) {
                    gates[(size_t)row*256 + col] = 1.f/(1.f + expf(-v));
                } else {
                    float c  = tanhf(v);
                    float u  = gates[(size_t)row*256 + 128 + col];
                    float ho = H[(size_t)row*HID + col];
                    float hn = u*ho + (1.f - u)*c;
                    hout[(size_t)row*HID + col] = hn;
                    if (out2) out2[(size_t)row*HID + col] = hn;
                }
            }
        }
    }
}

extern "C" void kernel_launch(void* const* d_in, const int* in_sizes, int n_in,
                              void* d_out, int out_size, void* d_ws, size_t ws_size,
                              hipStream_t stream) {
    (void)in_sizes; (void)n_in; (void)out_size; (void)ws_size;
    const float* inputs = (const float*)d_in[0];
    const float* h_init = (const float*)d_in[1];
    const float* S      = (const float*)d_in[2];
    const float* Wg0 = (const float*)d_in[3];
    const float* Wc0 = (const float*)d_in[5];
    const float* Wg1 = (const float*)d_in[7];
    const float* Wc1 = (const float*)d_in[9];
    const float* bg0 = (const float*)d_in[4];
    const float* bc0 = (const float*)d_in[6];
    const float* bg1 = (const float*)d_in[8];
    const float* bc1 = (const float*)d_in[10];

    float* out = (float*)d_out;
    float* outputs = out + 2*(size_t)BNH;

    // workspace carve-up (bytes)
    char* ws = (char*)d_ws;
    u16* A2bf = (u16*)ws;                         ws += 32768 * 2;
    u16* WTg0 = (u16*)ws;                         ws += 256*576 * 2;
    u16* WTc0 = (u16*)ws;                         ws += 128*576 * 2;
    u16* WTg1 = (u16*)ws;                         ws += 256*768 * 2;
    u16* WTc1 = (u16*)ws;                         ws += 128*768 * 2;
    ws = (char*)(((size_t)ws + 255) & ~(size_t)255);
    u16* xs = (u16*)ws;                           ws += (size_t)8192*512 * 2;   // 8MB
    float* gates = (float*)ws;                    ws += (size_t)8192*256 * 4;   // 8MB
    float* hA0 = (float*)ws;                      ws += (size_t)BNH * 4;
    float* hA1 = (float*)ws;                      ws += (size_t)BNH * 4;
    float* hB0 = (float*)ws;                      ws += (size_t)BNH * 4;
    float* hB1 = (float*)ws;                      ws += (size_t)BNH * 4;

    // init: hA <- h_init (hA0,hA1 adjacent)
    hipMemcpyAsync(hA0, h_init, (size_t)2*BNH*sizeof(float), hipMemcpyDeviceToDevice, stream);
    prep_A2_kernel<<<64, 256, 0, stream>>>(S, A2bf);
    prep_WT_kernel<<<(256*576+255)/256, 256, 0, stream>>>(Wg0, WTg0, 192, 256);
    prep_WT_kernel<<<(128*576+255)/256, 256, 0, stream>>>(Wc0, WTc0, 192, 128);
    prep_WT_kernel<<<(256*768+255)/256, 256, 0, stream>>>(Wg1, WTg1, 256, 256);
    prep_WT_kernel<<<(128*768+255)/256, 256, 0, stream>>>(Wc1, WTc1, 256, 128);

    for (int t = 0; t < SEQ; ++t) {
        const float* xt = inputs + (size_t)t * B * NN * IN_DIM;
        float* h0c = (t & 1) ? hB0 : hA0;  float* h0n = (t & 1) ? hA0 : hB0;
        float* h1c = (t & 1) ? hB1 : hA1;  float* h1n = (t & 1) ? hA1 : hB1;
        // ---- layer 0 (FIN=64, F=192) ----
        diffuse_mfma<64,192,false><<<dim3(2,3,B), 256, 0, stream>>>(xt, h0c, gates, A2bf, xs);
        proj_mfma<64,192,0><<<dim3(4,64), 256, 0, stream>>>(xt, h0c, xs, WTg0, bg0, gates, nullptr, nullptr);
        diffuse_mfma<64,192,true><<<dim3(2,3,B), 256, 0, stream>>>(xt, h0c, gates, A2bf, xs);
        proj_mfma<64,192,1><<<dim3(2,64), 256, 0, stream>>>(xt, h0c, xs, WTc0, bc0, gates, h0n, nullptr);
        // ---- layer 1 (FIN=128, F=256); x = new h0 ----
        diffuse_mfma<128,256,false><<<dim3(2,4,B), 256, 0, stream>>>(h0n, h1c, gates, A2bf, xs);
        proj_mfma<128,256,0><<<dim3(4,64), 256, 0, stream>>>(h0n, h1c, xs, WTg1, bg1, gates, nullptr, nullptr);
        diffuse_mfma<128,256,true><<<dim3(2,4,B), 256, 0, stream>>>(h0n, h1c, gates, A2bf, xs);
        proj_mfma<128,256,1><<<dim3(2,64), 256, 0, stream>>>(h0n, h1c, xs, WTc1, bc1, gates, h1n,
                                                            outputs + (size_t)t * BNH);
    }
    // final h (t=127 odd -> written into hA)
    hipMemcpyAsync(out, hA0, (size_t)2*BNH*sizeof(float), hipMemcpyDeviceToDevice, stream);
}

// Round 3
// 15979.128 us; speedup vs baseline: 2.7055x; 1.1687x over previous
//
#include <hip/hip_runtime.h>
#include <math.h>

#define SEQ 128
#define B 64
#define NN 128
#define IN_DIM 64
#define HID 128
#define BNH (B*NN*HID)   // 1,048,576

typedef unsigned short u16;
typedef __bf16 bf16x8 __attribute__((ext_vector_type(8)));
typedef float f32x4 __attribute__((ext_vector_type(4)));

__device__ __forceinline__ u16 f2bf(float f) {
    union { float f; unsigned u; } x; x.f = f;
    unsigned r = x.u + 0x7fffu + ((x.u >> 16) & 1u);
    return (u16)(r >> 16);
}
__device__ __forceinline__ float bf2f(u16 b) {
    union { unsigned u; float f; } x; x.u = ((unsigned)b) << 16; return x.f;
}
__device__ __forceinline__ bf16x8 ld_frag(const u16* p) {   // 16B aligned
    union { uint4 q; bf16x8 v; } u;
    u.q = *(const uint4*)p;
    return u.v;
}

// ---------------- one-time prep ----------------
__global__ void prep_A2_kernel(const float* __restrict__ S, u16* __restrict__ A2bf) {
    int idx = blockIdx.x * 256 + threadIdx.x;   // 16384
    int m = idx >> 7, n = idx & 127;
    A2bf[idx] = f2bf(S[idx]);
    float acc = 0.f;
    #pragma unroll 4
    for (int k = 0; k < 128; ++k) acc += S[m*128 + k] * S[k*128 + n];
    A2bf[16384 + idx] = f2bf(2.f*acc - (m == n ? 1.f : 0.f));
}

__global__ void prep_WT_kernel(const float* __restrict__ W, u16* __restrict__ WT,
                               int F, int NO) {
    int KK = 3 * F;
    int idx = blockIdx.x * 256 + threadIdx.x;
    if (idx >= NO * KK) return;
    int no = idx / KK, knew = idx - no * KK;
    int m = knew / F, f = knew - m * F;
    WT[idx] = f2bf(W[(size_t)(f*3 + m) * NO + no]);
}

__global__ void cast_f32_bf16(const float* __restrict__ in, u16* __restrict__ out, int n) {
    int i = blockIdx.x * 256 + threadIdx.x;
    if (i < n) out[i] = f2bf(in[i]);
}

// ---------------- D1: diffuse cat=[x,h]; write xs = [x0 | x1 | x2] bf16 ----------------
// block: 128 thr (2 waves), tile 64f x 64mp. grid (4 mp, F/64, B)
template<int FIN, int F, bool XF32>
__global__ __launch_bounds__(128) void diffuse1(
    const float* __restrict__ Xf, const u16* __restrict__ Xb,
    const u16* __restrict__ Hb, const u16* __restrict__ A2bf,
    u16* __restrict__ xs)
{
    __shared__ u16 At[64][40];    // [f][node]
    __shared__ u16 Bt[64][40];    // [mp][node]
    const int b   = blockIdx.z;
    const int f0  = blockIdx.y * 64;
    const int mp0 = blockIdx.x * 64;
    const int tid = threadIdx.x;
    const int lane = tid & 63, w = tid >> 6;
    const int l15 = lane & 15, l16 = lane >> 4;
    const int KK = 3 * F;

    f32x4 acc[2][4];
    #pragma unroll
    for (int i = 0; i < 2; ++i)
        #pragma unroll
        for (int j = 0; j < 4; ++j) acc[i][j] = (f32x4)(0.f);

    for (int kc = 0; kc < 4; ++kc) {
        const int n0 = kc * 32;
        {   // stage catT: nd = tid&31, fg = tid>>5 (4 groups of 16 f)
            int nd = tid & 31, fg = tid >> 5;
            int fb = f0 + fg * 16;
            int bn = b*NN + n0 + nd;
            union { uint4 q[2]; u16 s[16]; } tmp;
            if (fb < FIN) {
                if (XF32) {
                    const float4* p4 = (const float4*)(Xf + (size_t)bn*FIN + fb);
                    #pragma unroll
                    for (int g = 0; g < 4; ++g) {
                        float4 v = p4[g];
                        tmp.s[g*4+0] = f2bf(v.x); tmp.s[g*4+1] = f2bf(v.y);
                        tmp.s[g*4+2] = f2bf(v.z); tmp.s[g*4+3] = f2bf(v.w);
                    }
                } else {
                    const u16* p = Xb + (size_t)bn*FIN + fb;
                    tmp.q[0] = *(const uint4*)p;
                    tmp.q[1] = *(const uint4*)(p + 8);
                }
            } else {
                const u16* p = Hb + (size_t)bn*HID + (fb - FIN);
                tmp.q[0] = *(const uint4*)p;
                tmp.q[1] = *(const uint4*)(p + 8);
            }
            #pragma unroll
            for (int i = 0; i < 16; ++i) At[fg*16 + i][nd] = tmp.s[i];
        }
        {   // stage A2 tile: row = tid>>1, half = (tid&1)*16
            int row = tid >> 1, half = (tid & 1) * 16;
            const u16* p = A2bf + (size_t)(mp0 + row) * 128 + n0 + half;
            *(uint4*)&Bt[row][half]     = *(const uint4*)p;
            *(uint4*)&Bt[row][half + 8] = *(const uint4*)(p + 8);
        }
        __syncthreads();
        bf16x8 a[2], bb[4];
        #pragma unroll
        for (int i = 0; i < 2; ++i) a[i] = ld_frag(&At[w*32 + i*16 + l15][l16*8]);
        #pragma unroll
        for (int j = 0; j < 4; ++j) bb[j] = ld_frag(&Bt[j*16 + l15][l16*8]);
        #pragma unroll
        for (int i = 0; i < 2; ++i)
            #pragma unroll
            for (int j = 0; j < 4; ++j)
                acc[i][j] = __builtin_amdgcn_mfma_f32_16x16x32_bf16(a[i], bb[j], acc[i][j], 0, 0, 0);
        // x0 write-back (re-transpose from LDS), only mp-tile 0 blocks
        if (blockIdx.x == 0) {
            int nd = tid & 31, q = tid >> 5;
            unsigned pk[8];
            #pragma unroll
            for (int i = 0; i < 8; ++i)
                pk[i] = (unsigned)At[q*16 + 2*i][nd] | ((unsigned)At[q*16 + 2*i + 1][nd] << 16);
            u16* dst = xs + (size_t)(b*NN + n0 + nd) * KK + f0 + q*16;
            *(uint4*)dst       = make_uint4(pk[0], pk[1], pk[2], pk[3]);
            *(uint4*)(dst + 8) = make_uint4(pk[4], pk[5], pk[6], pk[7]);
        }
        __syncthreads();
    }
    #pragma unroll
    for (int i = 0; i < 2; ++i) {
        int fb = f0 + w*32 + i*16 + l16*4;
        #pragma unroll
        for (int j = 0; j < 4; ++j) {
            int mp = mp0 + j*16 + l15;
            int node = mp & 127, slot = mp >> 7;
            u16* dst = xs + ((size_t)(b*NN + node)) * KK + (1 + slot)*F + fb;
            uint2 pk;
            pk.x = (unsigned)f2bf(acc[i][j][0]) | ((unsigned)f2bf(acc[i][j][1]) << 16);
            pk.y = (unsigned)f2bf(acc[i][j][2]) | ((unsigned)f2bf(acc[i][j][3]) << 16);
            *(uint2*)dst = pk;
        }
    }
}

// ---------------- D2: diffuse rh (xsc[0:128)) -> xsc[128:384) ----------------
// block: 128 thr, tile 64f x 64mp. grid (4 mp, 2 f, B)
__global__ __launch_bounds__(128) void diffuse2(
    const u16* __restrict__ xsc, const u16* __restrict__ A2bf)
{
    __shared__ u16 At[64][40];
    __shared__ u16 Bt[64][40];
    const int b   = blockIdx.z;
    const int f0  = blockIdx.y * 64;
    const int mp0 = blockIdx.x * 64;
    const int tid = threadIdx.x;
    const int lane = tid & 63, w = tid >> 6;
    const int l15 = lane & 15, l16 = lane >> 4;

    f32x4 acc[2][4];
    #pragma unroll
    for (int i = 0; i < 2; ++i)
        #pragma unroll
        for (int j = 0; j < 4; ++j) acc[i][j] = (f32x4)(0.f);

    for (int kc = 0; kc < 4; ++kc) {
        const int n0 = kc * 32;
        {
            int nd = tid & 31, fg = tid >> 5;
            int bn = b*NN + n0 + nd;
            const u16* p = xsc + (size_t)bn * 384 + f0 + fg*16;
            union { uint4 q[2]; u16 s[16]; } tmp;
            tmp.q[0] = *(const uint4*)p;
            tmp.q[1] = *(const uint4*)(p + 8);
            #pragma unroll
            for (int i = 0; i < 16; ++i) At[fg*16 + i][nd] = tmp.s[i];
        }
        {
            int row = tid >> 1, half = (tid & 1) * 16;
            const u16* p = A2bf + (size_t)(mp0 + row) * 128 + n0 + half;
            *(uint4*)&Bt[row][half]     = *(const uint4*)p;
            *(uint4*)&Bt[row][half + 8] = *(const uint4*)(p + 8);
        }
        __syncthreads();
        bf16x8 a[2], bb[4];
        #pragma unroll
        for (int i = 0; i < 2; ++i) a[i] = ld_frag(&At[w*32 + i*16 + l15][l16*8]);
        #pragma unroll
        for (int j = 0; j < 4; ++j) bb[j] = ld_frag(&Bt[j*16 + l15][l16*8]);
        #pragma unroll
        for (int i = 0; i < 2; ++i)
            #pragma unroll
            for (int j = 0; j < 4; ++j)
                acc[i][j] = __builtin_amdgcn_mfma_f32_16x16x32_bf16(a[i], bb[j], acc[i][j], 0, 0, 0);
        __syncthreads();
    }
    #pragma unroll
    for (int i = 0; i < 2; ++i) {
        int fb = f0 + w*32 + i*16 + l16*4;
        #pragma unroll
        for (int j = 0; j < 4; ++j) {
            int mp = mp0 + j*16 + l15;
            int node = mp & 127, slot = mp >> 7;
            u16* dst = (u16*)xsc + ((size_t)(b*NN + node)) * 384 + 128 + slot*128 + fb;
            uint2 pk;
            pk.x = (unsigned)f2bf(acc[i][j][0]) | ((unsigned)f2bf(acc[i][j][1]) << 16);
            pk.y = (unsigned)f2bf(acc[i][j][2]) | ((unsigned)f2bf(acc[i][j][3]) << 16);
            *(uint2*)dst = pk;
        }
    }
}

// ---------------- P1: gates GEMM (8192 x KK) @ (KK x 256); r*h -> xsc, u -> ubuf ----------------
// block: 256 thr (4 waves), tile 64x64, K-step 64. grid (4, 128)
template<int F>
__global__ __launch_bounds__(256) void proj_g(
    const u16* __restrict__ xs, const u16* __restrict__ WT, const float* __restrict__ bias,
    const u16* __restrict__ hbf, u16* __restrict__ xsc, float* __restrict__ ubuf)
{
    const int KK = 3 * F;
    __shared__ u16 At[64][72];
    __shared__ u16 Bt[64][72];
    const int n0 = blockIdx.x * 64;
    const int m0 = blockIdx.y * 64;
    const int tid = threadIdx.x;
    const int lane = tid & 63, w = tid >> 6;
    const int wm = w & 1, wn = w >> 1;
    const int l15 = lane & 15, l16 = lane >> 4;
    const int arow = tid & 63, aq = tid >> 6;

    f32x4 acc[2][2];
    #pragma unroll
    for (int i = 0; i < 2; ++i)
        #pragma unroll
        for (int j = 0; j < 2; ++j) acc[i][j] = (f32x4)(0.f);

    for (int k0 = 0; k0 < KK; k0 += 64) {
        {
            const u16* p = xs + (size_t)(m0 + arow)*KK + k0 + aq*16;
            *(uint4*)&At[arow][aq*16]     = *(const uint4*)p;
            *(uint4*)&At[arow][aq*16 + 8] = *(const uint4*)(p + 8);
        }
        {
            const u16* p = WT + (size_t)(n0 + arow)*KK + k0 + aq*16;
            *(uint4*)&Bt[arow][aq*16]     = *(const uint4*)p;
            *(uint4*)&Bt[arow][aq*16 + 8] = *(const uint4*)(p + 8);
        }
        __syncthreads();
        #pragma unroll
        for (int kk = 0; kk < 2; ++kk) {
            bf16x8 a[2], bb[2];
            #pragma unroll
            for (int i = 0; i < 2; ++i) a[i] = ld_frag(&At[wm*32 + i*16 + l15][kk*32 + l16*8]);
            #pragma unroll
            for (int j = 0; j < 2; ++j) bb[j] = ld_frag(&Bt[wn*32 + j*16 + l15][kk*32 + l16*8]);
            #pragma unroll
            for (int i = 0; i < 2; ++i)
                #pragma unroll
                for (int j = 0; j < 2; ++j)
                    acc[i][j] = __builtin_amdgcn_mfma_f32_16x16x32_bf16(a[i], bb[j], acc[i][j], 0, 0, 0);
        }
        __syncthreads();
    }
    const bool is_r = (n0 < 128);
    #pragma unroll
    for (int i = 0; i < 2; ++i) {
        #pragma unroll
        for (int j = 0; j < 2; ++j) {
            int col = n0 + wn*32 + j*16 + l15;
            float bcol = bias[col];
            #pragma unroll
            for (int r = 0; r < 4; ++r) {
                int row = m0 + wm*32 + i*16 + l16*4 + r;
                float v = acc[i][j][r] + bcol;
                float s = 1.f/(1.f + expf(-v));
                if (is_r) {
                    float h = bf2f(hbf[(size_t)row*HID + col]);
                    xsc[(size_t)row*384 + col] = f2bf(s * h);
                } else {
                    ubuf[(size_t)row*HID + (col - 128)] = s;
                }
            }
        }
    }
}

// ---------------- P2: cand GEMM (8192 x KK) @ (KK x 128); fused GRU update ----------------
// block: 128 thr (2 waves), tile 64M x 32N, K-step 64. grid (4, 128)
template<int FIN, int F, bool OUT>
__global__ __launch_bounds__(128) void proj_c(
    const u16* __restrict__ xs, const u16* __restrict__ xsc,
    const u16* __restrict__ WT, const float* __restrict__ bias,
    const float* __restrict__ ubuf, float* __restrict__ hf, u16* __restrict__ hbf,
    float* __restrict__ out2)
{
    const int KK = 3 * F;
    __shared__ u16 At[64][72];
    __shared__ u16 Bt[32][72];
    const int n0 = blockIdx.x * 32;
    const int m0 = blockIdx.y * 64;
    const int tid = threadIdx.x;
    const int lane = tid & 63, w = tid >> 6;
    const int l15 = lane & 15, l16 = lane >> 4;

    f32x4 acc[2][2];
    #pragma unroll
    for (int i = 0; i < 2; ++i)
        #pragma unroll
        for (int j = 0; j < 2; ++j) acc[i][j] = (f32x4)(0.f);

    for (int k0 = 0; k0 < KK; k0 += 64) {
        {   // A: row = tid&63, q = tid>>6 : 4 x uint4 at cols q*32 + g*8
            int row = tid & 63, q = tid >> 6;
            int bn = m0 + row;
            #pragma unroll
            for (int g = 0; g < 4; ++g) {
                int k = k0 + q*32 + g*8;
                int m = k / F, rem = k - m*F;
                const u16* p = (rem < FIN) ? (xs + (size_t)bn*KK + k)
                                           : (xsc + (size_t)bn*384 + m*128 + (rem - FIN));
                *(uint4*)&At[row][q*32 + g*8] = *(const uint4*)p;
            }
        }
        {   // B: row = tid&31, q = tid>>5 : 2 x uint4 at cols q*16
            int row = tid & 31, q = tid >> 5;
            const u16* p = WT + (size_t)(n0 + row)*KK + k0 + q*16;
            *(uint4*)&Bt[row][q*16]     = *(const uint4*)p;
            *(uint4*)&Bt[row][q*16 + 8] = *(const uint4*)(p + 8);
        }
        __syncthreads();
        #pragma unroll
        for (int kk = 0; kk < 2; ++kk) {
            bf16x8 a[2], bb[2];
            #pragma unroll
            for (int i = 0; i < 2; ++i) a[i] = ld_frag(&At[w*32 + i*16 + l15][kk*32 + l16*8]);
            #pragma unroll
            for (int j = 0; j < 2; ++j) bb[j] = ld_frag(&Bt[j*16 + l15][kk*32 + l16*8]);
            #pragma unroll
            for (int i = 0; i < 2; ++i)
                #pragma unroll
                for (int j = 0; j < 2; ++j)
                    acc[i][j] = __builtin_amdgcn_mfma_f32_16x16x32_bf16(a[i], bb[j], acc[i][j], 0, 0, 0);
        }
        __syncthreads();
    }
    #pragma unroll
    for (int i = 0; i < 2; ++i) {
        #pragma unroll
        for (int j = 0; j < 2; ++j) {
            int col = n0 + j*16 + l15;
            float bcol = bias[col];
            #pragma unroll
            for (int r = 0; r < 4; ++r) {
                int row = m0 + w*32 + i*16 + l16*4 + r;
                float v = acc[i][j][r] + bcol;
                float c = tanhf(v);
                float u = ubuf[(size_t)row*HID + col];
                float ho = hf[(size_t)row*HID + col];
                float hn = u*ho + (1.f - u)*c;
                hf[(size_t)row*HID + col] = hn;
                hbf[(size_t)row*HID + col] = f2bf(hn);
                if (OUT) out2[(size_t)row*HID + col] = hn;
            }
        }
    }
}

extern "C" void kernel_launch(void* const* d_in, const int* in_sizes, int n_in,
                              void* d_out, int out_size, void* d_ws, size_t ws_size,
                              hipStream_t stream) {
    (void)in_sizes; (void)n_in; (void)out_size; (void)ws_size;
    const float* inputs = (const float*)d_in[0];
    const float* h_init = (const float*)d_in[1];
    const float* S      = (const float*)d_in[2];
    const float* Wg0 = (const float*)d_in[3];
    const float* bg0 = (const float*)d_in[4];
    const float* Wc0 = (const float*)d_in[5];
    const float* bc0 = (const float*)d_in[6];
    const float* Wg1 = (const float*)d_in[7];
    const float* bg1 = (const float*)d_in[8];
    const float* Wc1 = (const float*)d_in[9];
    const float* bc1 = (const float*)d_in[10];

    float* out = (float*)d_out;
    float* outputs = out + 2*(size_t)BNH;

    char* ws = (char*)d_ws;
    u16* A2bf = (u16*)ws;                         ws += 32768 * 2;
    u16* WTg0 = (u16*)ws;                         ws += 256*576 * 2;
    u16* WTc0 = (u16*)ws;                         ws += 128*576 * 2;
    u16* WTg1 = (u16*)ws;                         ws += 256*768 * 2;
    u16* WTc1 = (u16*)ws;                         ws += 128*768 * 2;
    ws = (char*)(((size_t)ws + 255) & ~(size_t)255);
    u16* xs   = (u16*)ws;                         ws += (size_t)8192*768 * 2;   // 12MB
    u16* xsc  = (u16*)ws;                         ws += (size_t)8192*384 * 2;   // 6MB
    float* ubuf = (float*)ws;                     ws += (size_t)8192*128 * 4;   // 4MB
    float* hf0  = (float*)ws;                     ws += (size_t)BNH * 4;
    float* hf1  = (float*)ws;                     ws += (size_t)BNH * 4;
    u16* hbf0 = (u16*)ws;                         ws += (size_t)BNH * 2;
    u16* hbf1 = (u16*)ws;                         ws += (size_t)BNH * 2;

    hipMemcpyAsync(hf0, h_init, (size_t)2*BNH*sizeof(float), hipMemcpyDeviceToDevice, stream);
    cast_f32_bf16<<<(2*BNH + 255)/256, 256, 0, stream>>>(h_init, hbf0, 2*BNH);
    prep_A2_kernel<<<64, 256, 0, stream>>>(S, A2bf);
    prep_WT_kernel<<<(256*576+255)/256, 256, 0, stream>>>(Wg0, WTg0, 192, 256);
    prep_WT_kernel<<<(128*576+255)/256, 256, 0, stream>>>(Wc0, WTc0, 192, 128);
    prep_WT_kernel<<<(256*768+255)/256, 256, 0, stream>>>(Wg1, WTg1, 256, 256);
    prep_WT_kernel<<<(128*768+255)/256, 256, 0, stream>>>(Wc1, WTc1, 256, 128);

    for (int t = 0; t < SEQ; ++t) {
        const float* xt = inputs + (size_t)t * B * NN * IN_DIM;
        // ---- layer 0 (FIN=64, F=192) ----
        diffuse1<64,192,true><<<dim3(4,3,B), 128, 0, stream>>>(xt, nullptr, hbf0, A2bf, xs);
        proj_g<192><<<dim3(4,128), 256, 0, stream>>>(xs, WTg0, bg0, hbf0, xsc, ubuf);
        diffuse2<<<dim3(4,2,B), 128, 0, stream>>>(xsc, A2bf);
        proj_c<64,192,false><<<dim3(4,128), 128, 0, stream>>>(xs, xsc, WTc0, bc0, ubuf, hf0, hbf0, nullptr);
        // ---- layer 1 (FIN=128, F=256): x = new h0 (bf16 shadow) ----
        diffuse1<128,256,false><<<dim3(4,4,B), 128, 0, stream>>>(nullptr, hbf0, hbf1, A2bf, xs);
        proj_g<256><<<dim3(4,128), 256, 0, stream>>>(xs, WTg1, bg1, hbf1, xsc, ubuf);
        diffuse2<<<dim3(4,2,B), 128, 0, stream>>>(xsc, A2bf);
        proj_c<128,256,true><<<dim3(4,128), 128, 0, stream>>>(xs, xsc, WTc1, bc1, ubuf, hf1, hbf1,
                                                              outputs + (size_t)t * BNH);
    }
    hipMemcpyAsync(out, hf0, (size_t)2*BNH*sizeof(float), hipMemcpyDeviceToDevice, stream);
}

// Round 4
// 10668.307 us; speedup vs baseline: 4.0524x; 1.4978x over previous
//
#include <hip/hip_runtime.h>
#include <math.h>

#define SEQ 128
#define B 64
#define NN 128
#define IN_DIM 64
#define HID 128
#define BNH (B*NN*HID)   // 1,048,576

typedef unsigned short u16;
typedef __bf16 bf16x8 __attribute__((ext_vector_type(8)));
typedef float f32x4 __attribute__((ext_vector_type(4)));

__device__ __forceinline__ u16 f2bf(float f) {
    union { float f; unsigned u; } x; x.f = f;
    unsigned r = x.u + 0x7fffu + ((x.u >> 16) & 1u);
    return (u16)(r >> 16);
}
__device__ __forceinline__ float bf2f(u16 b) {
    union { unsigned u; float f; } x; x.u = ((unsigned)b) << 16; return x.f;
}
__device__ __forceinline__ bf16x8 ld_frag(const u16* p) {   // 16B-aligned
    union { uint4 q; bf16x8 v; } u;
    u.q = *(const uint4*)p;
    return u.v;
}
__device__ __forceinline__ uint2 pack4(const f32x4& a) {
    uint2 pk;
    pk.x = (unsigned)f2bf(a[0]) | ((unsigned)f2bf(a[1]) << 16);
    pk.y = (unsigned)f2bf(a[2]) | ((unsigned)f2bf(a[3]) << 16);
    return pk;
}
__device__ __forceinline__ bf16x8 cvt8(const float* p) {
    float4 v0 = *(const float4*)p, v1 = *(const float4*)(p + 4);
    union { uint4 q; bf16x8 v; } t;
    t.q.x = (unsigned)f2bf(v0.x) | ((unsigned)f2bf(v0.y) << 16);
    t.q.y = (unsigned)f2bf(v0.z) | ((unsigned)f2bf(v0.w) << 16);
    t.q.z = (unsigned)f2bf(v1.x) | ((unsigned)f2bf(v1.y) << 16);
    t.q.w = (unsigned)f2bf(v1.z) | ((unsigned)f2bf(v1.w) << 16);
    return t.v;
}

// ---------------- one-time prep ----------------
__global__ void prep_A2_kernel(const float* __restrict__ S, u16* __restrict__ A2bf) {
    int idx = blockIdx.x * 256 + threadIdx.x;   // 16384
    int m = idx >> 7, n = idx & 127;
    A2bf[idx] = f2bf(S[idx]);
    float acc = 0.f;
    #pragma unroll 4
    for (int k = 0; k < 128; ++k) acc += S[m*128 + k] * S[k*128 + n];
    A2bf[16384 + idx] = f2bf(2.f*acc - (m == n ? 1.f : 0.f));
}

__global__ void prep_WT_kernel(const float* __restrict__ W, u16* __restrict__ WT,
                               int F, int NO) {
    int KK = 3 * F;
    int idx = blockIdx.x * 256 + threadIdx.x;
    if (idx >= NO * KK) return;
    int no = idx / KK, knew = idx - no * KK;
    int m = knew / F, f = knew - m * F;
    WT[idx] = f2bf(W[(size_t)(f*3 + m) * NO + no]);
}

__global__ void cast2_kernel(const float* __restrict__ in, u16* __restrict__ o0,
                             u16* __restrict__ o1) {
    int i = blockIdx.x * 256 + threadIdx.x;   // 2*BNH threads
    if (i < BNH) o0[i] = f2bf(in[i]);
    else o1[i - BNH] = f2bf(in[i]);
}

// =====================================================================
// Kernel A (gates path), one block per (b, nh, layer). 512 thr = 8 waves.
//  phase1: stage catT[f][n] in LDS        phase2: diffusion -> xsL (LDS) + xs (global, f<FIN)
//  phase3: gates proj half (N=128)        epilogue: nh0 -> r*h (bf16), nh1 -> u (f32)
// =====================================================================
template<int L>
__device__ __forceinline__ void bodyA(
    int b, int nh,
    const float* __restrict__ xf, const u16* __restrict__ xb,
    const u16* __restrict__ hb, const u16* __restrict__ A2,
    const u16* __restrict__ WT, const float* __restrict__ bias,
    u16* __restrict__ rh, float* __restrict__ ubuf, u16* __restrict__ xsg,
    u16* smem)
{
    constexpr int FIN = L ? 128 : 64;
    constexpr int F   = L ? 256 : 192;
    constexpr int KK  = 3 * F;
    constexpr int NP  = F + 8;       // xsL pitch (16B-aligned rows, 2-way banks)
    constexpr int NF  = F / 16;
    constexpr int NKC = KK / 32;
    const int tid = threadIdx.x;
    const int lane = tid & 63, w = tid >> 6;
    const int l15 = lane & 15, l16 = lane >> 4;

    // ---- phase 1: catT[f][n] pitch 136 ----
    {
        constexpr int NT = 128 * (F / 8);
        for (int task = tid; task < NT; task += 512) {
            int n = task & 127, f8 = (task >> 7) * 8;
            int bn = b * NN + n;
            union { uint4 q; u16 s[8]; } t;
            if (f8 < FIN) {
                if (L == 0) {
                    union { uint4 q; bf16x8 v; } c;
                    c.v = cvt8(xf + (size_t)bn * IN_DIM + f8);
                    t.q = c.q;
                } else {
                    t.q = *(const uint4*)(xb + (size_t)bn * HID + f8);
                }
            } else {
                t.q = *(const uint4*)(hb + (size_t)bn * HID + (f8 - FIN));
            }
            #pragma unroll
            for (int i = 0; i < 8; ++i) smem[(f8 + i) * 136 + n] = t.s[i];
        }
    }
    __syncthreads();

    // ---- phase 2: diffusion D[f][mp] = sum_n catT[f][n] * A2[mp][n] ----
    f32x4 dacc[2][NF];
    #pragma unroll
    for (int i = 0; i < 2; ++i)
        #pragma unroll
        for (int ff = 0; ff < NF; ++ff) dacc[i][ff] = (f32x4)(0.f);
    const int mp0 = w * 32;
    #pragma unroll
    for (int kc = 0; kc < 4; ++kc) {
        const int n0 = kc * 32;
        bf16x8 bfr[2];
        #pragma unroll
        for (int i = 0; i < 2; ++i)
            bfr[i] = ld_frag(A2 + (size_t)(mp0 + i*16 + l15) * 128 + n0 + l16*8);
        #pragma unroll
        for (int ff = 0; ff < NF; ++ff) {
            bf16x8 afr = ld_frag(smem + (ff*16 + l15) * 136 + n0 + l16*8);
            #pragma unroll
            for (int i = 0; i < 2; ++i)
                dacc[i][ff] = __builtin_amdgcn_mfma_f32_16x16x32_bf16(afr, bfr[i], dacc[i][ff], 0, 0, 0);
        }
    }
    __syncthreads();   // all catT reads done; smem is reused as xsL below

    // ---- write D -> xsL[mp][f] (LDS) and x-part to global xs ----
    #pragma unroll
    for (int i = 0; i < 2; ++i) {
        const int mp = mp0 + i*16 + l15;
        #pragma unroll
        for (int ff = 0; ff < NF; ++ff) {
            const int f = ff*16 + l16*4;
            uint2 pk = pack4(dacc[i][ff]);
            *(uint2*)(smem + mp * NP + f) = pk;
            if ((((mp0 + i*16) >> 7) == nh) && (f < FIN))
                *(uint2*)(xsg + ((size_t)(b*256 + mp)) * FIN + f) = pk;
        }
    }
    __syncthreads();

    // ---- phase 3: gates proj, M=128 nodes x N=128 (this nh half), K=KK ----
    const int mg = w & 1, ng = w >> 1;   // 2 row-groups x 4 col-groups
    f32x4 pacc[4][2];
    #pragma unroll
    for (int fi = 0; fi < 4; ++fi)
        #pragma unroll
        for (int gj = 0; gj < 2; ++gj) pacc[fi][gj] = (f32x4)(0.f);

    #pragma unroll
    for (int kc = 0; kc < NKC; ++kc) {
        const int k = kc * 32, m = k / F, f = k - m * F;
        bf16x8 bb[2];
        #pragma unroll
        for (int gj = 0; gj < 2; ++gj) {
            const int col = nh*128 + ng*32 + gj*16 + l15;
            bb[gj] = ld_frag(WT + (size_t)col * KK + k + l16*8);
        }
        #pragma unroll
        for (int fi = 0; fi < 4; ++fi) {
            const int node = mg*64 + fi*16 + l15;
            const int bn = b * NN + node;
            bf16x8 a;
            if (m == 0) {
                if (f < FIN) {
                    if (L == 0) a = cvt8(xf + (size_t)bn * IN_DIM + f + l16*8);
                    else        a = ld_frag(xb + (size_t)bn * HID + f + l16*8);
                } else {
                    a = ld_frag(hb + (size_t)bn * HID + (f - FIN) + l16*8);
                }
            } else {
                a = ld_frag(smem + ((m - 1)*128 + node) * NP + f + l16*8);
            }
            #pragma unroll
            for (int gj = 0; gj < 2; ++gj)
                pacc[fi][gj] = __builtin_amdgcn_mfma_f32_16x16x32_bf16(a, bb[gj], pacc[fi][gj], 0, 0, 0);
        }
    }
    // ---- epilogue ----
    #pragma unroll
    for (int fi = 0; fi < 4; ++fi) {
        #pragma unroll
        for (int gj = 0; gj < 2; ++gj) {
            const int colL = ng*32 + gj*16 + l15;
            const float bc = bias[nh*128 + colL];
            #pragma unroll
            for (int r = 0; r < 4; ++r) {
                const int node = mg*64 + fi*16 + l16*4 + r;
                const int bn = b * NN + node;
                const float v = pacc[fi][gj][r] + bc;
                const float s = 1.f / (1.f + expf(-v));
                if (nh == 0) {
                    float h = bf2f(hb[(size_t)bn * HID + colL]);
                    rh[(size_t)bn * HID + colL] = f2bf(s * h);
                } else {
                    ubuf[(size_t)bn * HID + colL] = s;
                }
            }
        }
    }
}

// =====================================================================
// Kernel B (cand path), one block per (b, nh, layer). nh splits N=128 -> 64.
//  phase1: stage rhT      phase2: diffuse rh -> xsL2 (LDS)
//  phase3: cand proj half, fused GRU update epilogue
// =====================================================================
template<int L>
__device__ __forceinline__ void bodyB(
    int b, int nh,
    const float* __restrict__ xf, const u16* __restrict__ xb,
    const u16* __restrict__ rh, const float* __restrict__ ubuf,
    const u16* __restrict__ xsg, const u16* __restrict__ A2,
    const u16* __restrict__ WT, const float* __restrict__ bias,
    const float* __restrict__ hfR, float* __restrict__ hfW,
    u16* __restrict__ hbfW, float* __restrict__ out2,
    u16* smem)
{
    constexpr int FIN = L ? 128 : 64;
    constexpr int F   = L ? 256 : 192;
    constexpr int KK  = 3 * F;
    constexpr int NKC = KK / 32;
    const int tid = threadIdx.x;
    const int lane = tid & 63, w = tid >> 6;
    const int l15 = lane & 15, l16 = lane >> 4;
    u16* xsL2 = smem + 128 * 136;    // [256][136]

    // ---- phase 1: rhT[f][n] pitch 136 (rh width = HID) ----
    for (int task = tid; task < 128 * 16; task += 512) {
        int n = task & 127, f8 = (task >> 7) * 8;
        union { uint4 q; u16 s[8]; } t;
        t.q = *(const uint4*)(rh + (size_t)(b * NN + n) * HID + f8);
        #pragma unroll
        for (int i = 0; i < 8; ++i) smem[(f8 + i) * 136 + n] = t.s[i];
    }
    __syncthreads();

    // ---- phase 2: diffuse rh: D[f][mp], f<128 ----
    f32x4 dacc[2][8];
    #pragma unroll
    for (int i = 0; i < 2; ++i)
        #pragma unroll
        for (int ff = 0; ff < 8; ++ff) dacc[i][ff] = (f32x4)(0.f);
    const int mp0 = w * 32;
    #pragma unroll
    for (int kc = 0; kc < 4; ++kc) {
        const int n0 = kc * 32;
        bf16x8 bfr[2];
        #pragma unroll
        for (int i = 0; i < 2; ++i)
            bfr[i] = ld_frag(A2 + (size_t)(mp0 + i*16 + l15) * 128 + n0 + l16*8);
        #pragma unroll
        for (int ff = 0; ff < 8; ++ff) {
            bf16x8 afr = ld_frag(smem + (ff*16 + l15) * 136 + n0 + l16*8);
            #pragma unroll
            for (int i = 0; i < 2; ++i)
                dacc[i][ff] = __builtin_amdgcn_mfma_f32_16x16x32_bf16(afr, bfr[i], dacc[i][ff], 0, 0, 0);
        }
    }
    // write to xsL2 (separate region; no overlay with rhT)
    #pragma unroll
    for (int i = 0; i < 2; ++i) {
        const int mp = mp0 + i*16 + l15;
        #pragma unroll
        for (int ff = 0; ff < 8; ++ff) {
            const int f = ff*16 + l16*4;
            *(uint2*)(xsL2 + mp * 136 + f) = pack4(dacc[i][ff]);
        }
    }
    __syncthreads();

    // ---- phase 3: cand proj, M=128 x N=64 (nh half), K=KK ----
    const int mg = w & 1, ng = w >> 1;   // 2 row-groups x 4 col-groups of 16
    f32x4 cacc[4];
    #pragma unroll
    for (int fi = 0; fi < 4; ++fi) cacc[fi] = (f32x4)(0.f);

    #pragma unroll
    for (int kc = 0; kc < NKC; ++kc) {
        const int k = kc * 32, m = k / F, f = k - m * F;
        const int col = nh*64 + ng*16 + l15;
        bf16x8 bb = ld_frag(WT + (size_t)col * KK + k + l16*8);
        #pragma unroll
        for (int fi = 0; fi < 4; ++fi) {
            const int node = mg*64 + fi*16 + l15;
            const int bn = b * NN + node;
            bf16x8 a;
            if (m == 0) {
                if (f < FIN) {
                    if (L == 0) a = cvt8(xf + (size_t)bn * IN_DIM + f + l16*8);
                    else        a = ld_frag(xb + (size_t)bn * HID + f + l16*8);
                } else {
                    a = ld_frag(rh + (size_t)bn * HID + (f - FIN) + l16*8);
                }
            } else {
                if (f < FIN) a = ld_frag(xsg + ((size_t)(b*256 + (m-1)*128 + node)) * FIN + f + l16*8);
                else         a = ld_frag(xsL2 + ((m-1)*128 + node) * 136 + (f - FIN) + l16*8);
            }
            cacc[fi] = __builtin_amdgcn_mfma_f32_16x16x32_bf16(a, bb, cacc[fi], 0, 0, 0);
        }
    }
    // ---- epilogue: GRU update ----
    #pragma unroll
    for (int fi = 0; fi < 4; ++fi) {
        const int colL = nh*64 + ng*16 + l15;
        const float bc = bias[colL];
        #pragma unroll
        for (int r = 0; r < 4; ++r) {
            const int node = mg*64 + fi*16 + l16*4 + r;
            const int bn = b * NN + node;
            const float v = cacc[fi][r] + bc;
            const float c = tanhf(v);
            const float u = ubuf[(size_t)bn * HID + colL];
            const float ho = hfR[(size_t)bn * HID + colL];
            const float hn = u * ho + (1.f - u) * c;
            hfW[(size_t)bn * HID + colL] = hn;
            hbfW[(size_t)bn * HID + colL] = f2bf(hn);
            if (L == 1) out2[(size_t)bn * HID + colL] = hn;
        }
    }
}

__global__ __launch_bounds__(512, 2) void kA(int zoff,
    const float* xf0, const u16* h0r, const u16* h1b, const u16* A2,
    const u16* WTg0, const float* bg0, u16* rh0, float* u0, u16* xs0,
    const u16* WTg1, const float* bg1, u16* rh1, float* u1, u16* xs1)
{
    extern __shared__ u16 smem[];
    const int b = blockIdx.x, nh = blockIdx.y;
    if ((int)blockIdx.z + zoff == 0)
        bodyA<0>(b, nh, xf0, nullptr, h0r, A2, WTg0, bg0, rh0, u0, xs0, smem);
    else
        bodyA<1>(b, nh, nullptr, h0r, h1b, A2, WTg1, bg1, rh1, u1, xs1, smem);
}

__global__ __launch_bounds__(512, 2) void kB(int zoff,
    const float* xf0, const u16* h0r, const u16* A2,
    const u16* rh0, const float* u0, const u16* xs0, const u16* WTc0, const float* bc0,
    const float* hf0r, float* hf0w, u16* hbf0w,
    const u16* rh1, const float* u1, const u16* xs1, const u16* WTc1, const float* bc1,
    float* hf1, u16* hbf1, float* out2)
{
    extern __shared__ u16 smem[];
    const int b = blockIdx.x, nh = blockIdx.y;
    if ((int)blockIdx.z + zoff == 0)
        bodyB<0>(b, nh, xf0, nullptr, rh0, u0, xs0, A2, WTc0, bc0, hf0r, hf0w, hbf0w, nullptr, smem);
    else
        bodyB<1>(b, nh, nullptr, h0r, rh1, u1, xs1, A2, WTc1, bc1, hf1, hf1, hbf1, out2, smem);
}

extern "C" void kernel_launch(void* const* d_in, const int* in_sizes, int n_in,
                              void* d_out, int out_size, void* d_ws, size_t ws_size,
                              hipStream_t stream) {
    (void)in_sizes; (void)n_in; (void)out_size; (void)ws_size;
    const float* inputs = (const float*)d_in[0];
    const float* h_init = (const float*)d_in[1];
    const float* S      = (const float*)d_in[2];
    const float* Wg0 = (const float*)d_in[3];
    const float* bg0 = (const float*)d_in[4];
    const float* Wc0 = (const float*)d_in[5];
    const float* bc0 = (const float*)d_in[6];
    const float* Wg1 = (const float*)d_in[7];
    const float* bg1 = (const float*)d_in[8];
    const float* Wc1 = (const float*)d_in[9];
    const float* bc1 = (const float*)d_in[10];

    float* out = (float*)d_out;
    float* outputs = out + 2 * (size_t)BNH;

    char* ws = (char*)d_ws;
    u16* A2bf = (u16*)ws;                       ws += 32768 * 2;
    u16* WTg0 = (u16*)ws;                       ws += 256*576 * 2;
    u16* WTc0 = (u16*)ws;                       ws += 128*576 * 2;
    u16* WTg1 = (u16*)ws;                       ws += 256*768 * 2;
    u16* WTc1 = (u16*)ws;                       ws += 128*768 * 2;
    ws = (char*)(((size_t)ws + 255) & ~(size_t)255);
    u16* xs0 = (u16*)ws;                        ws += (size_t)64*256*64 * 2;    // 2MB
    u16* xs1 = (u16*)ws;                        ws += (size_t)64*256*128 * 2;   // 4MB
    u16* rh0 = (u16*)ws;                        ws += (size_t)BNH * 2;
    u16* rh1 = (u16*)ws;                        ws += (size_t)BNH * 2;
    float* u0 = (float*)ws;                     ws += (size_t)BNH * 4;
    float* u1 = (float*)ws;                     ws += (size_t)BNH * 4;
    float* hf0_[2];
    hf0_[0] = (float*)ws;                       ws += (size_t)BNH * 4;
    hf0_[1] = (float*)ws;                       ws += (size_t)BNH * 4;
    float* hf1 = (float*)ws;                    ws += (size_t)BNH * 4;
    u16* hbf0_[2];
    hbf0_[0] = (u16*)ws;                        ws += (size_t)BNH * 2;
    hbf0_[1] = (u16*)ws;                        ws += (size_t)BNH * 2;
    u16* hbf1 = (u16*)ws;                       ws += (size_t)BNH * 2;

    hipFuncSetAttribute((const void*)kA, hipFuncAttributeMaxDynamicSharedMemorySize, 135168);
    hipFuncSetAttribute((const void*)kB, hipFuncAttributeMaxDynamicSharedMemorySize, 110592);

    // init: h_init -> hf0_[1], hf1 (f32) and hbf0_[1], hbf1 (bf16)
    hipMemcpyAsync(hf0_[1], h_init, (size_t)BNH * sizeof(float), hipMemcpyDeviceToDevice, stream);
    hipMemcpyAsync(hf1, h_init + BNH, (size_t)BNH * sizeof(float), hipMemcpyDeviceToDevice, stream);
    cast2_kernel<<<(2*BNH + 255)/256, 256, 0, stream>>>(h_init, hbf0_[1], hbf1);
    prep_A2_kernel<<<64, 256, 0, stream>>>(S, A2bf);
    prep_WT_kernel<<<(256*576 + 255)/256, 256, 0, stream>>>(Wg0, WTg0, 192, 256);
    prep_WT_kernel<<<(128*576 + 255)/256, 256, 0, stream>>>(Wc0, WTc0, 192, 128);
    prep_WT_kernel<<<(256*768 + 255)/256, 256, 0, stream>>>(Wg1, WTg1, 256, 256);
    prep_WT_kernel<<<(128*768 + 255)/256, 256, 0, stream>>>(Wc1, WTc1, 256, 128);

    for (int tau = 0; tau <= SEQ; ++tau) {
        const int nz = (tau == 0 || tau == SEQ) ? 1 : 2;
        const int zoff = (tau == SEQ) ? 1 : 0;
        const int rb = (tau + 1) & 1, wb = tau & 1;
        const int tx = (tau < SEQ) ? tau : (SEQ - 1);
        const float* xt = inputs + (size_t)tx * B * NN * IN_DIM;
        const u16* h0r = hbf0_[rb];
        float* out2 = outputs + (size_t)((tau > 0) ? tau - 1 : 0) * BNH;

        kA<<<dim3(64, 2, nz), 512, 135168, stream>>>(zoff,
            xt, h0r, hbf1, A2bf,
            WTg0, bg0, rh0, u0, xs0,
            WTg1, bg1, rh1, u1, xs1);
        kB<<<dim3(64, 2, nz), 512, 110592, stream>>>(zoff,
            xt, h0r, A2bf,
            rh0, u0, xs0, WTc0, bc0, hf0_[rb], hf0_[wb], hbf0_[wb],
            rh1, u1, xs1, WTc1, bc1, hf1, hbf1, out2);
    }
    // final hidden: h0[127] is in hf0_[127&1 = 1], h1[127] in hf1
    hipMemcpyAsync(out, hf0_[1], (size_t)BNH * sizeof(float), hipMemcpyDeviceToDevice, stream);
    hipMemcpyAsync(out + BNH, hf1, (size_t)BNH * sizeof(float), hipMemcpyDeviceToDevice, stream);
}

// Round 5
// 8465.697 us; speedup vs baseline: 5.1068x; 1.2602x over previous
//
#include <hip/hip_runtime.h>
#include <math.h>

#define SEQ 128
#define B 64
#define NN 128
#define IN_DIM 64
#define HID 128
#define BNH (B*NN*HID)   // 1,048,576

typedef unsigned short u16;
typedef __bf16 bf16x8 __attribute__((ext_vector_type(8)));
typedef float f32x4 __attribute__((ext_vector_type(4)));

__device__ __forceinline__ u16 f2bf(float f) {
    union { float f; unsigned u; } x; x.f = f;
    unsigned r = x.u + 0x7fffu + ((x.u >> 16) & 1u);
    return (u16)(r >> 16);
}
__device__ __forceinline__ float bf2f(u16 b) {
    union { unsigned u; float f; } x; x.u = ((unsigned)b) << 16; return x.f;
}
__device__ __forceinline__ bf16x8 ld_frag(const u16* p) {   // 16B-aligned
    union { uint4 q; bf16x8 v; } u;
    u.q = *(const uint4*)p;
    return u.v;
}
__device__ __forceinline__ uint2 pack4(const f32x4& a) {
    uint2 pk;
    pk.x = (unsigned)f2bf(a[0]) | ((unsigned)f2bf(a[1]) << 16);
    pk.y = (unsigned)f2bf(a[2]) | ((unsigned)f2bf(a[3]) << 16);
    return pk;
}
__device__ __forceinline__ bf16x8 cvt8(const float* p) {
    float4 v0 = *(const float4*)p, v1 = *(const float4*)(p + 4);
    union { uint4 q; bf16x8 v; } t;
    t.q.x = (unsigned)f2bf(v0.x) | ((unsigned)f2bf(v0.y) << 16);
    t.q.y = (unsigned)f2bf(v0.z) | ((unsigned)f2bf(v0.w) << 16);
    t.q.z = (unsigned)f2bf(v1.x) | ((unsigned)f2bf(v1.y) << 16);
    t.q.w = (unsigned)f2bf(v1.z) | ((unsigned)f2bf(v1.w) << 16);
    return t.v;
}

// ---------------- one-time prep ----------------
__global__ void prep_A2_kernel(const float* __restrict__ S, u16* __restrict__ A2bf) {
    int idx = blockIdx.x * 256 + threadIdx.x;   // 16384
    int m = idx >> 7, n = idx & 127;
    A2bf[idx] = f2bf(S[idx]);
    float acc = 0.f;
    #pragma unroll 4
    for (int k = 0; k < 128; ++k) acc += S[m*128 + k] * S[k*128 + n];
    A2bf[16384 + idx] = f2bf(2.f*acc - (m == n ? 1.f : 0.f));
}

// frag-major A2: [kc(4)][g(16)][lane(64)][8]; col=mp=g*16+(lane&15), k=n=kc*32+(lane>>4)*8+j
__global__ void prep_A2f_kernel(const u16* __restrict__ A2bf, u16* __restrict__ A2f) {
    int idx = blockIdx.x * 256 + threadIdx.x;   // 32768
    int j = idx & 7, lane = (idx >> 3) & 63, g = (idx >> 9) & 15, kc = idx >> 13;
    int mp = g*16 + (lane & 15);
    int n  = kc*32 + (lane >> 4)*8 + j;
    A2f[idx] = A2bf[mp*128 + n];
}

// frag-major WT: [kc][cg(NO/16)][lane][8]; col=cg*16+(lane&15), k=kc*32+(lane>>4)*8+j
// source: W[f*3+m][col] with k = m*F + f
__global__ void prep_WTf_kernel(const float* __restrict__ W, u16* __restrict__ WTf,
                                int F, int NO) {
    int KK = 3 * F;
    int idx = blockIdx.x * 256 + threadIdx.x;
    if (idx >= NO * KK) return;
    int per = 512 * (NO/16);
    int kc = idx / per, rem = idx % per;
    int cg = rem >> 9, lane = (rem >> 3) & 63, j = idx & 7;
    int col = cg*16 + (lane & 15);
    int k = kc*32 + (lane >> 4)*8 + j;
    int m = k / F, f = k - m*F;
    WTf[idx] = f2bf(W[(size_t)(f*3 + m) * NO + col]);
}

__global__ void cast2_kernel(const float* __restrict__ in, u16* __restrict__ o0,
                             u16* __restrict__ o1) {
    int i = blockIdx.x * 256 + threadIdx.x;
    if (i < BNH) o0[i] = f2bf(in[i]);
    else o1[i - BNH] = f2bf(in[i]);
}

// =====================================================================
// kA: gates path. grid (64 b, 2 nh(N-half), z layers), 512 thr.
//  ph1 catT[f][128] (XOR-swz) ; ph2 diffusion -> xsL[256][F] (overlay) + xsgF (f<FIN)
//  ph3 gates proj (M=128, N=128-half, K=3F) ; epi: nh0 -> r*h, nh1 -> u
// =====================================================================
template<int L>
__device__ __forceinline__ void bodyA(
    int b, int nh,
    const float* __restrict__ xf, const u16* __restrict__ xb,
    const u16* __restrict__ hb, const u16* __restrict__ A2f,
    const u16* __restrict__ WTf, const float* __restrict__ bias,
    u16* __restrict__ rh, float* __restrict__ ubuf, u16* __restrict__ xsgF,
    u16* smem)
{
    constexpr int FIN = L ? 128 : 64;
    constexpr int F   = L ? 256 : 192;
    constexpr int KK  = 3 * F;
    const int tid = threadIdx.x;
    const int lane = tid & 63, w = tid >> 6;
    const int l15 = lane & 15, l16 = lane >> 4;

    // ---- ph1: stage catT[f][n], XOR-swizzled ----
    for (int task = tid; task < 128 * (F/8); task += 512) {
        int n = task & 127, f8 = (task >> 7) * 8;
        int bn = b*NN + n;
        union { uint4 q; u16 s[8]; } t;
        if (f8 < FIN) {
            if (L == 0) { union { uint4 q; bf16x8 v; } c; c.v = cvt8(xf + (size_t)bn*IN_DIM + f8); t.q = c.q; }
            else t.q = *(const uint4*)(xb + (size_t)bn*HID + f8);
        } else t.q = *(const uint4*)(hb + (size_t)bn*HID + (f8 - FIN));
        #pragma unroll
        for (int i = 0; i < 8; ++i)
            smem[(f8+i)*128 + (n ^ (((f8+i) & 7)*8))] = t.s[i];
    }
    __syncthreads();

    // ---- ph2: D[f][mp]; wave = mp-64 (w&3) x f-F/2 (w>>2) ----
    constexpr int NFW = F / 32;
    const int mg2 = w & 3, fg2 = w >> 2;
    const int f0w = fg2 * (F/2);
    f32x4 dacc[NFW][4];
    #pragma unroll
    for (int ff = 0; ff < NFW; ++ff)
        #pragma unroll
        for (int mm = 0; mm < 4; ++mm) dacc[ff][mm] = (f32x4)(0.f);

    #pragma unroll
    for (int kc = 0; kc < 4; ++kc) {
        bf16x8 bfr[4];
        #pragma unroll
        for (int mm = 0; mm < 4; ++mm)
            bfr[mm] = ld_frag(A2f + ((kc*16 + mg2*4 + mm)*64 + lane)*8);
        #pragma unroll
        for (int ff = 0; ff < NFW; ++ff) {
            const int f = f0w + ff*16 + l15;
            bf16x8 afr = ld_frag(&smem[f*128 + ((kc*32 + l16*8) ^ ((f & 7)*8))]);
            #pragma unroll
            for (int mm = 0; mm < 4; ++mm)
                dacc[ff][mm] = __builtin_amdgcn_mfma_f32_16x16x32_bf16(afr, bfr[mm], dacc[ff][mm], 0, 0, 0);
        }
    }
    __syncthreads();   // catT dead; overlay as xsL

    // ---- write xsL[mp][F] (XOR-swz) + xsgF (frag-major global, f<FIN) ----
    #pragma unroll
    for (int ff = 0; ff < NFW; ++ff) {
        const int f4 = f0w + ff*16 + l16*4;
        #pragma unroll
        for (int mm = 0; mm < 4; ++mm) {
            const int mp = mg2*64 + mm*16 + l15;
            uint2 pk = pack4(dacc[ff][mm]);
            *(uint2*)&smem[mp*F + (f4 ^ ((mp & 7)*8))] = pk;
            if (f4 < FIN) {
                const int slot = mp >> 7, node = mp & 127;
                size_t off = ((((size_t)b*2 + slot)*(FIN/32) + (f4 >> 5))*8 + (node >> 4))*512
                           + (((f4 >> 3) & 3)*16 + (node & 15))*8 + (f4 & 7);
                *(uint2*)(xsgF + off) = pk;
            }
        }
    }
    __syncthreads();

    // ---- ph3: proj M=128 x N=128(nh), K=KK; wave = M-64 (w&1) x N-32 (w>>1) ----
    const int mg = w & 1, ng = w >> 1;
    f32x4 pacc[4][2];
    #pragma unroll
    for (int fi = 0; fi < 4; ++fi)
        #pragma unroll
        for (int gj = 0; gj < 2; ++gj) pacc[fi][gj] = (f32x4)(0.f);

    #pragma unroll
    for (int kc = 0; kc < KK/32; ++kc) {
        const int k = kc*32, m = k / F, fIn = k - m*F;
        bf16x8 bb[2];
        #pragma unroll
        for (int gj = 0; gj < 2; ++gj)
            bb[gj] = ld_frag(WTf + (((size_t)kc*16 + nh*8 + ng*2 + gj)*64 + lane)*8);
        #pragma unroll
        for (int fi = 0; fi < 4; ++fi) {
            const int node = mg*64 + fi*16 + l15;
            bf16x8 a;
            if (m == 0) {
                const int bn = b*NN + node, f = fIn + l16*8;
                if (f < FIN) {
                    if (L == 0) a = cvt8(xf + (size_t)bn*IN_DIM + f);
                    else        a = ld_frag(xb + (size_t)bn*HID + f);
                } else a = ld_frag(hb + (size_t)bn*HID + (f - FIN));
            } else {
                const int mp = (m-1)*128 + node;
                a = ld_frag(&smem[mp*F + ((fIn + l16*8) ^ ((mp & 7)*8))]);
            }
            #pragma unroll
            for (int gj = 0; gj < 2; ++gj)
                pacc[fi][gj] = __builtin_amdgcn_mfma_f32_16x16x32_bf16(a, bb[gj], pacc[fi][gj], 0, 0, 0);
        }
    }
    // ---- epilogue ----
    #pragma unroll
    for (int fi = 0; fi < 4; ++fi) {
        #pragma unroll
        for (int gj = 0; gj < 2; ++gj) {
            const int colL = ng*32 + gj*16 + l15;
            const float bc = bias[nh*128 + colL];
            #pragma unroll
            for (int r = 0; r < 4; ++r) {
                const int node = mg*64 + fi*16 + l16*4 + r;
                const int bn = b*NN + node;
                const float v = pacc[fi][gj][r] + bc;
                const float s = 1.f / (1.f + expf(-v));
                if (nh == 0) {
                    float h = bf2f(hb[(size_t)bn*HID + colL]);
                    rh[(size_t)bn*HID + colL] = f2bf(s * h);
                } else {
                    ubuf[(size_t)bn*HID + colL] = s;
                }
            }
        }
    }
}

// =====================================================================
// kB: cand path. grid (64 b, 2 nh(M-half), z layers), 512 thr.
//  ph1 rhT[128][128] + catN[64][CW] ; ph2 diffuse rh (its 128 mp rows) -> xsL2
//  ph3 cand proj (M=64, N=128, K=3F) + fused GRU
// =====================================================================
template<int L>
__device__ __forceinline__ void bodyB(
    int b, int nh,
    const float* __restrict__ xf, const u16* __restrict__ xb,
    const u16* __restrict__ rh, const float* __restrict__ ubuf,
    const u16* __restrict__ xsgF, const u16* __restrict__ A2f,
    const u16* __restrict__ WTf, const float* __restrict__ bias,
    const float* __restrict__ hfR, float* __restrict__ hfW,
    u16* __restrict__ hbfW, float* __restrict__ out2,
    u16* smem)
{
    constexpr int FIN = L ? 128 : 64;
    constexpr int F   = L ? 256 : 192;
    constexpr int KK  = 3 * F;
    constexpr int CW  = FIN + 128;
    u16* rhT  = smem;                  // [128][128] XOR
    u16* catN = smem + 128*128;        // [64][CW]  XOR
    u16* xsL2 = catN + 64*CW;          // [128][128] XOR
    const int tid = threadIdx.x;
    const int lane = tid & 63, w = tid >> 6;
    const int l15 = lane & 15, l16 = lane >> 4;

    // ---- ph1a: rhT (all 128 nodes) ----
    for (int task = tid; task < 128*16; task += 512) {
        int n = task & 127, f8 = (task >> 7) * 8;
        union { uint4 q; u16 s[8]; } t;
        t.q = *(const uint4*)(rh + (size_t)(b*NN + n)*HID + f8);
        #pragma unroll
        for (int i = 0; i < 8; ++i)
            rhT[(f8+i)*128 + (n ^ (((f8+i) & 7)*8))] = t.s[i];
    }
    // ---- ph1b: catN rows (this nh's 64 nodes), row-major vec writes ----
    for (int task = tid; task < 64*(CW/8); task += 512) {
        int nl = task & 63, f8 = (task >> 6) * 8;
        int bn = b*NN + nh*64 + nl;
        uint4 q;
        if (f8 < FIN) {
            if (L == 0) { union { uint4 q; bf16x8 v; } c; c.v = cvt8(xf + (size_t)bn*IN_DIM + f8); q = c.q; }
            else q = *(const uint4*)(xb + (size_t)bn*HID + f8);
        } else q = *(const uint4*)(rh + (size_t)bn*HID + (f8 - FIN));
        *(uint4*)&catN[nl*CW + (f8 ^ ((nl & 7)*8))] = q;
    }
    __syncthreads();

    // ---- ph2: D2[f 128][ml 128]; ml = slot*64+nl (this nh); wave = f-64 (w>>2) x ml-32 (w&3) ----
    const int mgB = w & 3, fgB = w >> 2;
    const int f0w = fgB*64, ml0 = mgB*32;
    f32x4 dacc[4][2];
    #pragma unroll
    for (int ff = 0; ff < 4; ++ff)
        #pragma unroll
        for (int mm = 0; mm < 2; ++mm) dacc[ff][mm] = (f32x4)(0.f);

    #pragma unroll
    for (int kc = 0; kc < 4; ++kc) {
        bf16x8 bfr[2];
        #pragma unroll
        for (int mm = 0; mm < 2; ++mm) {
            const int mlb = ml0 + mm*16;
            const int g = (mlb >> 6)*8 + nh*4 + ((mlb & 63) >> 4);
            bfr[mm] = ld_frag(A2f + ((kc*16 + g)*64 + lane)*8);
        }
        #pragma unroll
        for (int ff = 0; ff < 4; ++ff) {
            const int f = f0w + ff*16 + l15;
            bf16x8 afr = ld_frag(&rhT[f*128 + ((kc*32 + l16*8) ^ ((f & 7)*8))]);
            #pragma unroll
            for (int mm = 0; mm < 2; ++mm)
                dacc[ff][mm] = __builtin_amdgcn_mfma_f32_16x16x32_bf16(afr, bfr[mm], dacc[ff][mm], 0, 0, 0);
        }
    }
    #pragma unroll
    for (int ff = 0; ff < 4; ++ff) {
        const int f4 = f0w + ff*16 + l16*4;
        #pragma unroll
        for (int mm = 0; mm < 2; ++mm) {
            const int ml = ml0 + mm*16 + l15;
            *(uint2*)&xsL2[ml*128 + (f4 ^ ((ml & 7)*8))] = pack4(dacc[ff][mm]);
        }
    }
    __syncthreads();

    // ---- ph3: cand proj M=64 x N=128, K=KK; wave = M-32 (w&1) x N-32 (w>>1) ----
    const int mg = w & 1, ng = w >> 1;
    f32x4 cacc[2][2];
    #pragma unroll
    for (int fi = 0; fi < 2; ++fi)
        #pragma unroll
        for (int gj = 0; gj < 2; ++gj) cacc[fi][gj] = (f32x4)(0.f);

    #pragma unroll
    for (int kc = 0; kc < KK/32; ++kc) {
        const int k = kc*32, m = k / F, fIn = k - m*F;
        bf16x8 bb[2];
        #pragma unroll
        for (int gj = 0; gj < 2; ++gj)
            bb[gj] = ld_frag(WTf + (((size_t)kc*8 + ng*2 + gj)*64 + lane)*8);
        #pragma unroll
        for (int fi = 0; fi < 2; ++fi) {
            const int nl = mg*32 + fi*16 + l15;
            bf16x8 a;
            if (m == 0) {
                a = ld_frag(&catN[nl*CW + ((fIn + l16*8) ^ ((nl & 7)*8))]);
            } else if (fIn < FIN) {
                size_t off = ((((size_t)b*2 + (m-1))*(FIN/32) + (fIn >> 5))*8 + (nh*4 + mg*2 + fi))*512
                           + (size_t)lane*8;
                a = ld_frag(xsgF + off);
            } else {
                const int ml = (m-1)*64 + nl;
                a = ld_frag(&xsL2[ml*128 + (((fIn - FIN) + l16*8) ^ ((ml & 7)*8))]);
            }
            #pragma unroll
            for (int gj = 0; gj < 2; ++gj)
                cacc[fi][gj] = __builtin_amdgcn_mfma_f32_16x16x32_bf16(a, bb[gj], cacc[fi][gj], 0, 0, 0);
        }
    }
    // ---- epilogue: GRU ----
    #pragma unroll
    for (int fi = 0; fi < 2; ++fi) {
        #pragma unroll
        for (int gj = 0; gj < 2; ++gj) {
            const int col = ng*32 + gj*16 + l15;
            const float bc = bias[col];
            #pragma unroll
            for (int r = 0; r < 4; ++r) {
                const int node = nh*64 + mg*32 + fi*16 + l16*4 + r;
                const int bn = b*NN + node;
                const float v = cacc[fi][gj][r] + bc;
                const float c = tanhf(v);
                const float u = ubuf[(size_t)bn*HID + col];
                const float ho = hfR[(size_t)bn*HID + col];
                const float hn = u*ho + (1.f - u)*c;
                hfW[(size_t)bn*HID + col] = hn;
                hbfW[(size_t)bn*HID + col] = f2bf(hn);
                if (L == 1) out2[(size_t)bn*HID + col] = hn;
            }
        }
    }
}

__global__ __launch_bounds__(512, 2) void kA(int zoff,
    const float* xf0, const u16* h0r, const u16* h1b, const u16* A2f,
    const u16* WTgf0, const float* bg0, u16* rh0, float* u0, u16* xsgF0,
    const u16* WTgf1, const float* bg1, u16* rh1, float* u1, u16* xsgF1)
{
    extern __shared__ u16 smem[];
    const int b = blockIdx.x, nh = blockIdx.y;
    if ((int)blockIdx.z + zoff == 0)
        bodyA<0>(b, nh, xf0, nullptr, h0r, A2f, WTgf0, bg0, rh0, u0, xsgF0, smem);
    else
        bodyA<1>(b, nh, nullptr, h0r, h1b, A2f, WTgf1, bg1, rh1, u1, xsgF1, smem);
}

__global__ __launch_bounds__(512, 2) void kB(int zoff,
    const float* xf0, const u16* h0r, const u16* A2f,
    const u16* rh0, const float* u0, const u16* xsgF0, const u16* WTcf0, const float* bc0,
    const float* hf0r, float* hf0w, u16* hbf0w,
    const u16* rh1, const float* u1, const u16* xsgF1, const u16* WTcf1, const float* bc1,
    float* hf1, u16* hbf1, float* out2)
{
    extern __shared__ u16 smem[];
    const int b = blockIdx.x, nh = blockIdx.y;
    if ((int)blockIdx.z + zoff == 0)
        bodyB<0>(b, nh, xf0, nullptr, rh0, u0, xsgF0, A2f, WTcf0, bc0, hf0r, hf0w, hbf0w, nullptr, smem);
    else
        bodyB<1>(b, nh, nullptr, h0r, rh1, u1, xsgF1, A2f, WTcf1, bc1, hf1, hf1, hbf1, out2, smem);
}

extern "C" void kernel_launch(void* const* d_in, const int* in_sizes, int n_in,
                              void* d_out, int out_size, void* d_ws, size_t ws_size,
                              hipStream_t stream) {
    (void)in_sizes; (void)n_in; (void)out_size; (void)ws_size;
    const float* inputs = (const float*)d_in[0];
    const float* h_init = (const float*)d_in[1];
    const float* S      = (const float*)d_in[2];
    const float* Wg0 = (const float*)d_in[3];
    const float* bg0 = (const float*)d_in[4];
    const float* Wc0 = (const float*)d_in[5];
    const float* bc0 = (const float*)d_in[6];
    const float* Wg1 = (const float*)d_in[7];
    const float* bg1 = (const float*)d_in[8];
    const float* Wc1 = (const float*)d_in[9];
    const float* bc1 = (const float*)d_in[10];

    float* out = (float*)d_out;
    float* outputs = out + 2 * (size_t)BNH;

    char* ws = (char*)d_ws;
    u16* A2bf  = (u16*)ws;                      ws += 32768 * 2;
    u16* A2f   = (u16*)ws;                      ws += 32768 * 2;
    u16* WTgf0 = (u16*)ws;                      ws += 256*576 * 2;
    u16* WTcf0 = (u16*)ws;                      ws += 128*576 * 2;
    u16* WTgf1 = (u16*)ws;                      ws += 256*768 * 2;
    u16* WTcf1 = (u16*)ws;                      ws += 128*768 * 2;
    ws = (char*)(((size_t)ws + 255) & ~(size_t)255);
    u16* xsgF0 = (u16*)ws;                      ws += (size_t)64*2*2*4096 * 2;  // 2MB
    u16* xsgF1 = (u16*)ws;                      ws += (size_t)64*2*4*4096 * 2;  // 4MB
    u16* rh0 = (u16*)ws;                        ws += (size_t)BNH * 2;
    u16* rh1 = (u16*)ws;                        ws += (size_t)BNH * 2;
    float* u0 = (float*)ws;                     ws += (size_t)BNH * 4;
    float* u1 = (float*)ws;                     ws += (size_t)BNH * 4;
    float* hf0_[2];
    hf0_[0] = (float*)ws;                       ws += (size_t)BNH * 4;
    hf0_[1] = (float*)ws;                       ws += (size_t)BNH * 4;
    float* hf1 = (float*)ws;                    ws += (size_t)BNH * 4;
    u16* hbf0_[2];
    hbf0_[0] = (u16*)ws;                        ws += (size_t)BNH * 2;
    hbf0_[1] = (u16*)ws;                        ws += (size_t)BNH * 2;
    u16* hbf1 = (u16*)ws;                       ws += (size_t)BNH * 2;

    hipFuncSetAttribute((const void*)kA, hipFuncAttributeMaxDynamicSharedMemorySize, 131072);
    hipFuncSetAttribute((const void*)kB, hipFuncAttributeMaxDynamicSharedMemorySize, 98304);

    hipMemcpyAsync(hf0_[1], h_init, (size_t)BNH * sizeof(float), hipMemcpyDeviceToDevice, stream);
    hipMemcpyAsync(hf1, h_init + BNH, (size_t)BNH * sizeof(float), hipMemcpyDeviceToDevice, stream);
    cast2_kernel<<<(2*BNH + 255)/256, 256, 0, stream>>>(h_init, hbf0_[1], hbf1);
    prep_A2_kernel<<<64, 256, 0, stream>>>(S, A2bf);
    prep_A2f_kernel<<<128, 256, 0, stream>>>(A2bf, A2f);
    prep_WTf_kernel<<<(256*576 + 255)/256, 256, 0, stream>>>(Wg0, WTgf0, 192, 256);
    prep_WTf_kernel<<<(128*576 + 255)/256, 256, 0, stream>>>(Wc0, WTcf0, 192, 128);
    prep_WTf_kernel<<<(256*768 + 255)/256, 256, 0, stream>>>(Wg1, WTgf1, 256, 256);
    prep_WTf_kernel<<<(128*768 + 255)/256, 256, 0, stream>>>(Wc1, WTcf1, 256, 128);

    for (int tau = 0; tau <= SEQ; ++tau) {
        const int nz = (tau == 0 || tau == SEQ) ? 1 : 2;
        const int zoff = (tau == SEQ) ? 1 : 0;
        const int rb = (tau + 1) & 1, wb = tau & 1;
        const int tx = (tau < SEQ) ? tau : (SEQ - 1);
        const float* xt = inputs + (size_t)tx * B * NN * IN_DIM;
        const u16* h0r = hbf0_[rb];
        float* out2 = outputs + (size_t)((tau > 0) ? tau - 1 : 0) * BNH;

        kA<<<dim3(64, 2, nz), 512, 131072, stream>>>(zoff,
            xt, h0r, hbf1, A2f,
            WTgf0, bg0, rh0, u0, xsgF0,
            WTgf1, bg1, rh1, u1, xsgF1);
        kB<<<dim3(64, 2, nz), 512, 98304, stream>>>(zoff,
            xt, h0r, A2f,
            rh0, u0, xsgF0, WTcf0, bc0, hf0_[rb], hf0_[wb], hbf0_[wb],
            rh1, u1, xsgF1, WTcf1, bc1, hf1, hbf1, out2);
    }
    hipMemcpyAsync(out, hf0_[1], (size_t)BNH * sizeof(float), hipMemcpyDeviceToDevice, stream);
    hipMemcpyAsync(out + BNH, hf1, (size_t)BNH * sizeof(float), hipMemcpyDeviceToDevice, stream);
}